// Round 2
// baseline (1191.429 us; speedup 1.0000x reference)
//
#include <hip/hip_runtime.h>
#include <hip/hip_bf16.h>
#include <stdint.h>

// RouteCapsule: I=1024 in-caps (D=64), O=32 out-caps (E=64), B=64, 3 routing iters.
// Inputs fp32 (x: [I][B][D], route_w: [O][I][D][E]); output fp32 [O][B][E].
// Heavy passes are bf16-MFMA GEMMs streaming route_w; u is never materialized.

#define IC 1024
#define OC 32
#define DD 64
#define EE 64
#define BB 64

typedef __attribute__((ext_vector_type(8))) short short8;
typedef __attribute__((ext_vector_type(16))) float f32x16;

__device__ __forceinline__ unsigned short f2bf(float f) {
    unsigned int u = __float_as_uint(f);
    u = (u + 0x7FFFu + ((u >> 16) & 1u)) >> 16;   // RNE
    return (unsigned short)u;
}
__device__ __forceinline__ unsigned int pk2(float a, float b) {
    return (unsigned int)f2bf(a) | ((unsigned int)f2bf(b) << 16);
}

// ---------------------------------------------------------------------------
// s[o,b,e] += sum_i sum_d (c[o,i,b] * x[i,b,d]) * w[o,i,d,e]
// grid = (ichunk=32, o=32), 256 thr (4 waves), wave = (bh,eh) quadrant of 64x64.
// ---------------------------------------------------------------------------
template<bool UNIFORM>
__global__ __launch_bounds__(256)
void gemm_s_kernel(const float* __restrict__ x,
                   const float* __restrict__ w,
                   const float* __restrict__ cbuf,
                   float* __restrict__ s_out)
{
    __shared__ unsigned short xs[64 * 68];   // [b][d] bf16, stride 68
    __shared__ unsigned short wT[64 * 68];   // [e][d] bf16 (B-operand wants k=d runs)
    const int t = threadIdx.x;
    const int o = blockIdx.y;
    const int chunk = blockIdx.x;
    const int lane = t & 63;
    const int wv = t >> 6;
    const int bh = wv & 1, eh = wv >> 1;
    const int seg = t & 7;
    const int rrow = t >> 3;

    f32x16 acc = (f32x16)0.0f;

    for (int ii = 0; ii < 32; ++ii) {
        const int i = chunk * 32 + ii;
        __syncthreads();
        // stage scaled x rows b = rrow, rrow+32 (fp32 -> bf16)
        for (int hlf = 0; hlf < 2; ++hlf) {
            const int b = rrow + hlf * 32;
            const float* xp = x + (((size_t)i) * BB + b) * DD + seg * 8;
            const float4 xa = *(const float4*)xp;
            const float4 xb = *(const float4*)(xp + 4);
            float c;
            if (UNIFORM) c = 1.0f / 32.0f;
            else         c = cbuf[(((size_t)o) * IC + i) * BB + b];
            uint2* dst = (uint2*)&xs[b * 68 + seg * 8];
            dst[0] = make_uint2(pk2(xa.x * c, xa.y * c), pk2(xa.z * c, xa.w * c));
            dst[1] = make_uint2(pk2(xb.x * c, xb.y * c), pk2(xb.z * c, xb.w * c));
        }
        // stage w transposed: thread loads rows d0,d0+1, writes d-pairs per e
        {
            const int d0 = rrow * 2;
            const float* wp = w + ((((size_t)o) * IC + i) * DD + d0) * EE + seg * 8;
            const float4 a0 = *(const float4*)(wp);
            const float4 a1 = *(const float4*)(wp + 4);
            const float4 b0 = *(const float4*)(wp + EE);
            const float4 b1 = *(const float4*)(wp + EE + 4);
            const float r0[8] = {a0.x, a0.y, a0.z, a0.w, a1.x, a1.y, a1.z, a1.w};
            const float r1[8] = {b0.x, b0.y, b0.z, b0.w, b1.x, b1.y, b1.z, b1.w};
            #pragma unroll
            for (int j = 0; j < 8; ++j) {
                const int e = seg * 8 + j;
                *(unsigned int*)&wT[e * 68 + d0] = pk2(r0[j], r1[j]);
            }
        }
        __syncthreads();
        #pragma unroll
        for (int kk = 0; kk < 4; ++kk) {
            const int k0 = kk * 16 + (lane >> 5) * 8;        // d offset
            const int ar = bh * 32 + (lane & 31);            // A row = b
            const int br = eh * 32 + (lane & 31);            // B col = e
            uint2 alo = *(const uint2*)&xs[ar * 68 + k0];
            uint2 ahi = *(const uint2*)&xs[ar * 68 + k0 + 4];
            uint2 blo = *(const uint2*)&wT[br * 68 + k0];
            uint2 bhi = *(const uint2*)&wT[br * 68 + k0 + 4];
            union { uint4 u; short8 s; } au, bu;
            au.u = make_uint4(alo.x, alo.y, ahi.x, ahi.y);
            bu.u = make_uint4(blo.x, blo.y, bhi.x, bhi.y);
            acc = __builtin_amdgcn_mfma_f32_32x32x16_bf16(au.s, bu.s, acc, 0, 0, 0);
        }
    }
    // C layout (m74/m101): col = lane&31, row = (r&3)+8*(r>>2)+4*(lane>>5)
    #pragma unroll
    for (int r = 0; r < 16; ++r) {
        const int gb = bh * 32 + (r & 3) + 8 * (r >> 2) + 4 * (lane >> 5);
        const int ge = eh * 32 + (lane & 31);
        atomicAdd(&s_out[(((size_t)o) * BB + gb) * EE + ge], acc[r]);
    }
}

// ---------------------------------------------------------------------------
// Per i (grid=1024): for each o, T[d,b] = sum_e w[o,i,d,e]*v[o,b,e] via MFMA
// (contraction over e = contiguous axis of both w and v -> no transpose),
// logit L[o,b] = sum_d x[i,b,d]*T[d,b] (+ bprev). Softmax over o is local.
// Writes c[o,i,b]; FIRST also writes b1[o,i,b].
// ---------------------------------------------------------------------------
template<bool FIRST>
__global__ __launch_bounds__(256)
void logits_kernel(const float* __restrict__ x,
                   const float* __restrict__ w,
                   const unsigned short* __restrict__ vbuf,   // [O][B][E] bf16
                   const float* __restrict__ bprev,           // [O][I][B] (iter2)
                   float* __restrict__ bout,                  // [O][I][B] (iter1)
                   float* __restrict__ cbuf)                  // [O][I][B]
{
    __shared__ float xT[64 * 65];              // xT[d][b] fp32, pad 65
    __shared__ unsigned short wls[64 * 68];    // w[d][e] bf16, stride 68
    __shared__ unsigned short vls[64 * 68];    // v[b][e] bf16, stride 68
    __shared__ float Lp[OC][2][BB];            // per-o, per-d-half logit partials
    const int t = threadIdx.x;
    const int i = blockIdx.x;
    const int lane = t & 63;
    const int wv = t >> 6;
    const int dh = wv & 1, bh = wv >> 1;
    const int seg = t & 7;
    const int rrow = t >> 3;

    for (int hlf = 0; hlf < 2; ++hlf) {        // stage xT (transposed, fp32)
        const int b = rrow + hlf * 32;
        const float* xp = x + (((size_t)i) * BB + b) * DD + seg * 8;
        const float4 xa = *(const float4*)xp;
        const float4 xb = *(const float4*)(xp + 4);
        const float xv[8] = {xa.x, xa.y, xa.z, xa.w, xb.x, xb.y, xb.z, xb.w};
        #pragma unroll
        for (int j = 0; j < 8; ++j)
            xT[(seg * 8 + j) * 65 + b] = xv[j];
    }

    for (int o = 0; o < OC; ++o) {
        __syncthreads();
        for (int hlf = 0; hlf < 2; ++hlf) {
            const int d = rrow + hlf * 32;
            const float* wp = w + ((((size_t)o) * IC + i) * DD + d) * EE + seg * 8;
            const float4 wa = *(const float4*)wp;
            const float4 wb = *(const float4*)(wp + 4);
            uint2* dst = (uint2*)&wls[d * 68 + seg * 8];
            dst[0] = make_uint2(pk2(wa.x, wa.y), pk2(wa.z, wa.w));
            dst[1] = make_uint2(pk2(wb.x, wb.y), pk2(wb.z, wb.w));
            const int b = d;
            const uint4 vr = *(const uint4*)(vbuf + (((size_t)o) * BB + b) * EE + seg * 8);
            uint2* vdst = (uint2*)&vls[b * 68 + seg * 8];
            vdst[0] = make_uint2(vr.x, vr.y);
            vdst[1] = make_uint2(vr.z, vr.w);
        }
        __syncthreads();
        f32x16 acc = (f32x16)0.0f;
        #pragma unroll
        for (int kk = 0; kk < 4; ++kk) {
            const int k0 = kk * 16 + (lane >> 5) * 8;        // e offset
            const int dr = dh * 32 + (lane & 31);            // A row = d
            const int br = bh * 32 + (lane & 31);            // B col = b
            uint2 alo = *(const uint2*)&wls[dr * 68 + k0];
            uint2 ahi = *(const uint2*)&wls[dr * 68 + k0 + 4];
            uint2 blo = *(const uint2*)&vls[br * 68 + k0];
            uint2 bhi = *(const uint2*)&vls[br * 68 + k0 + 4];
            union { uint4 u; short8 s; } au, bu;
            au.u = make_uint4(alo.x, alo.y, ahi.x, ahi.y);
            bu.u = make_uint4(blo.x, blo.y, bhi.x, bhi.y);
            acc = __builtin_amdgcn_mfma_f32_32x32x16_bf16(au.s, bu.s, acc, 0, 0, 0);
        }
        // L[b] partial = sum_r xT[d(r)][b] * T[d(r),b]
        float partial = 0.f;
        const int bcol = bh * 32 + (lane & 31);
        #pragma unroll
        for (int r = 0; r < 16; ++r) {
            const int d = dh * 32 + (r & 3) + 8 * (r >> 2) + 4 * (lane >> 5);
            partial += xT[d * 65 + bcol] * acc[r];
        }
        partial += __shfl_xor(partial, 32);    // fold the two k-half lane groups
        if (lane < 32) Lp[o][dh][bcol] = partial;
    }
    __syncthreads();
    if (t < BB) {                              // softmax over o, one thread per b
        const int b = t;
        float lt[OC];
        float m = -1e30f;
        #pragma unroll
        for (int o = 0; o < OC; ++o) {
            float L = Lp[o][0][b] + Lp[o][1][b];
            if (!FIRST) L += bprev[(((size_t)o) * IC + i) * BB + b];
            if (FIRST)  bout[(((size_t)o) * IC + i) * BB + b] = L;
            lt[o] = L;
            m = fmaxf(m, L);
        }
        float Z = 0.f;
        #pragma unroll
        for (int o = 0; o < OC; ++o) { lt[o] = __expf(lt[o] - m); Z += lt[o]; }
        const float rZ = 1.0f / Z;
        #pragma unroll
        for (int o = 0; o < OC; ++o)
            cbuf[(((size_t)o) * IC + i) * BB + b] = lt[o] * rZ;
    }
}

// v = squash(s): scale = sqrt(|s|^2) / (1 + |s|^2), per [o,b] row of 64.
// TOBF: write bf16 (MFMA operand for logits); else fp32 (final output).
template<bool TOBF>
__global__ __launch_bounds__(256)
void squash_kernel(const float* __restrict__ s, void* __restrict__ vout)
{
    const int o = blockIdx.x;
    const int lane = threadIdx.x & 63;
    const int wv = threadIdx.x >> 6;
    for (int b = wv; b < BB; b += 4) {
        const float val = s[(((size_t)o) * BB + b) * EE + lane];
        float sq = val * val;
        #pragma unroll
        for (int off = 1; off < 64; off <<= 1)
            sq += __shfl_xor(sq, off);
        const float r = sqrtf(sq);
        const float scale = r / (1.0f + sq);
        const size_t idx = (((size_t)o) * BB + b) * EE + lane;
        if (TOBF) ((unsigned short*)vout)[idx] = f2bf(val * scale);
        else      ((float*)vout)[idx] = val * scale;
    }
}

extern "C" void kernel_launch(void* const* d_in, const int* in_sizes, int n_in,
                              void* d_out, int out_size, void* d_ws, size_t ws_size,
                              hipStream_t stream)
{
    const float* x = (const float*)d_in[0];   // [I][B][D] fp32
    const float* w = (const float*)d_in[1];   // [O][I][D][E] fp32
    float* out = (float*)d_out;               // [O][B][E] fp32

    char* ws = (char*)d_ws;
    float*          s_buf = (float*)ws;                                   // 512 KB
    unsigned short* vbuf  = (unsigned short*)(ws + 524288);               // 256 KB bf16
    float*          b1    = (float*)(ws + 524288 + 262144);               // 8 MB
    float*          cbuf  = (float*)(ws + 524288 + 262144 + 8388608);     // 8 MB

    const dim3 gridG(32, 32), blk(256);

    // iter 0: c = 1/32 uniform -> s0 -> v0
    hipMemsetAsync(s_buf, 0, 524288, stream);
    gemm_s_kernel<true><<<gridG, blk, 0, stream>>>(x, w, nullptr, s_buf);
    squash_kernel<true><<<32, 256, 0, stream>>>(s_buf, vbuf);
    // iter 1: b1 = u.v0, c1 = softmax_o(b1), s1, v1
    logits_kernel<true><<<1024, 256, 0, stream>>>(x, w, vbuf, nullptr, b1, cbuf);
    hipMemsetAsync(s_buf, 0, 524288, stream);
    gemm_s_kernel<false><<<gridG, blk, 0, stream>>>(x, w, cbuf, s_buf);
    squash_kernel<true><<<32, 256, 0, stream>>>(s_buf, vbuf);
    // iter 2: b2 = b1 + u.v1, c2 = softmax_o(b2), s2, v2 -> out (fp32)
    logits_kernel<false><<<1024, 256, 0, stream>>>(x, w, vbuf, b1, nullptr, cbuf);
    hipMemsetAsync(s_buf, 0, 524288, stream);
    gemm_s_kernel<false><<<gridG, blk, 0, stream>>>(x, w, cbuf, s_buf);
    squash_kernel<false><<<32, 256, 0, stream>>>(s_buf, out);
}